// Round 1
// baseline (2999.749 us; speedup 1.0000x reference)
//
#include <hip/hip_runtime.h>

#define NROWS 32768
#define DIM   1024
#define HIDD  512
#define M3    (3*NROWS)

// ---------- helpers ----------
static __device__ __forceinline__ unsigned short f2bf(float f) {
    unsigned u = __float_as_uint(f);
    u += 0x7FFFu + ((u >> 16) & 1u);   // round-to-nearest-even
    return (unsigned short)(u >> 16);
}
static __device__ __forceinline__ float bf2f(unsigned short s) {
    return __uint_as_float(((unsigned)s) << 16);
}

// ---------- GEMM1: h[r][c] = leaky(bn(x[r]·W1[c] + b1[c])), h bf16 [3N][512] ----------
// grid (8, 1536): x = col-block (8 of 64), y = row-block (1536 of 64). 256 thr, 4x4/thread.
__global__ __launch_bounds__(256)
void gemm1_kernel(const float* __restrict__ x0, const float* __restrict__ x1,
                  const float* __restrict__ x2,
                  const float* __restrict__ W1, const float* __restrict__ b1,
                  const float* __restrict__ gamma, const float* __restrict__ beta,
                  const float* __restrict__ rmean, const float* __restrict__ rvar,
                  unsigned short* __restrict__ h)
{
    __shared__ float As[32][68];
    __shared__ float Bs[32][68];
    const int cb = blockIdx.x;          // 0..7
    const int rb = blockIdx.y;          // 0..1535
    const int tid = threadIdx.x;
    const int tx = tid & 15, ty = tid >> 4;
    const int row0 = rb * 64;
    const int s = row0 >> 15;           // stream
    const float* x = (s == 0) ? x0 : (s == 1 ? x1 : x2);
    const int rl0 = row0 & (NROWS - 1);

    float acc[4][4] = {};
    for (int k0 = 0; k0 < DIM; k0 += 32) {
        #pragma unroll
        for (int it = 0; it < 2; ++it) {
            int f  = tid + it * 256;     // 0..511
            int rr = f >> 3;             // 0..63
            int kq = f & 7;              // 0..7
            float4 v = *reinterpret_cast<const float4*>(&x[(size_t)(rl0 + rr) * DIM + k0 + kq * 4]);
            As[kq*4+0][rr] = v.x; As[kq*4+1][rr] = v.y;
            As[kq*4+2][rr] = v.z; As[kq*4+3][rr] = v.w;
            float4 w = *reinterpret_cast<const float4*>(&W1[(size_t)(cb*64 + rr) * DIM + k0 + kq * 4]);
            Bs[kq*4+0][rr] = w.x; Bs[kq*4+1][rr] = w.y;
            Bs[kq*4+2][rr] = w.z; Bs[kq*4+3][rr] = w.w;
        }
        __syncthreads();
        #pragma unroll
        for (int kk = 0; kk < 32; ++kk) {
            const float4 a = *reinterpret_cast<const float4*>(&As[kk][ty*4]);
            const float4 b = *reinterpret_cast<const float4*>(&Bs[kk][tx*4]);
            const float av[4] = {a.x, a.y, a.z, a.w};
            const float bv[4] = {b.x, b.y, b.z, b.w};
            #pragma unroll
            for (int i = 0; i < 4; ++i)
                #pragma unroll
                for (int j = 0; j < 4; ++j)
                    acc[i][j] = fmaf(av[i], bv[j], acc[i][j]);
        }
        __syncthreads();
    }
    #pragma unroll
    for (int j = 0; j < 4; ++j) {
        const int c   = cb*64 + tx*4 + j;
        const float inv = rsqrtf(rvar[c] + 1e-5f);
        const float g = gamma[c], bt = beta[c], mu = rmean[c], bb = b1[c];
        #pragma unroll
        for (int i = 0; i < 4; ++i) {
            const int r = row0 + ty*4 + i;
            float v = acc[i][j] + bb;
            v = (v - mu) * inv * g + bt;
            v = (v >= 0.f) ? v : 0.1f * v;
            h[(size_t)r * HIDD + c] = f2bf(v);
        }
    }
}

// ---------- GEMM2 fused: e = h·W2^T + b2 for a/p/n; reduce distances + L2 ----------
// grid (16, 1024): x = col-block (16 of 64 cols of DIM), y = row-block (1024 of 32 rows of N).
// 256 thr: tx=cols (4 each), ty=rows (2 each). Never materializes e.
__global__ __launch_bounds__(256)
void gemm2_kernel(const unsigned short* __restrict__ h,
                  const float* __restrict__ W2, const float* __restrict__ b2,
                  float* __restrict__ pdp, float* __restrict__ pdn,
                  float* __restrict__ pl2)
{
    __shared__ float As[3][32][36];
    __shared__ float Bs[32][68];
    __shared__ float wred[4];
    const int cb = blockIdx.x;          // 0..15
    const int rb = blockIdx.y;          // 0..1023
    const int tid = threadIdx.x;
    const int tx = tid & 15, ty = tid >> 4;

    float acc[3][2][4] = {};
    for (int k0 = 0; k0 < HIDD; k0 += 32) {
        {   // stage h tiles (bf16 -> f32), one ushort4 per thread per stream
            const int rr = tid >> 3;     // 0..31
            const int kq = tid & 7;      // 0..7
            #pragma unroll
            for (int s = 0; s < 3; ++s) {
                ushort4 hv = *reinterpret_cast<const ushort4*>(
                    &h[((size_t)s * NROWS + (size_t)rb * 32 + rr) * HIDD + k0 + kq * 4]);
                As[s][kq*4+0][rr] = bf2f(hv.x);
                As[s][kq*4+1][rr] = bf2f(hv.y);
                As[s][kq*4+2][rr] = bf2f(hv.z);
                As[s][kq*4+3][rr] = bf2f(hv.w);
            }
            #pragma unroll
            for (int it = 0; it < 2; ++it) {
                int f  = tid + it * 256;
                int rr2 = f >> 3;        // 0..63
                int kq2 = f & 7;
                float4 w = *reinterpret_cast<const float4*>(
                    &W2[(size_t)(cb*64 + rr2) * HIDD + k0 + kq2 * 4]);
                Bs[kq2*4+0][rr2] = w.x; Bs[kq2*4+1][rr2] = w.y;
                Bs[kq2*4+2][rr2] = w.z; Bs[kq2*4+3][rr2] = w.w;
            }
        }
        __syncthreads();
        #pragma unroll
        for (int kk = 0; kk < 32; ++kk) {
            const float4 b = *reinterpret_cast<const float4*>(&Bs[kk][tx*4]);
            const float bv[4] = {b.x, b.y, b.z, b.w};
            #pragma unroll
            for (int s = 0; s < 3; ++s) {
                const float2 a = *reinterpret_cast<const float2*>(&As[s][kk][ty*2]);
                #pragma unroll
                for (int j = 0; j < 4; ++j) {
                    acc[s][0][j] = fmaf(a.x, bv[j], acc[s][0][j]);
                    acc[s][1][j] = fmaf(a.y, bv[j], acc[s][1][j]);
                }
            }
        }
        __syncthreads();
    }

    // epilogue: add b2, per-row partial reductions
    float tdp[2] = {0.f, 0.f}, tdn[2] = {0.f, 0.f};
    float tl2 = 0.f;
    #pragma unroll
    for (int j = 0; j < 4; ++j) {
        const float bb = b2[cb*64 + tx*4 + j];
        #pragma unroll
        for (int i = 0; i < 2; ++i) {
            const float ea = acc[0][i][j] + bb;
            const float ep = acc[1][i][j] + bb;
            const float en = acc[2][i][j] + bb;
            const float dp = ea - ep, dn = ea - en;
            tdp[i] += dp * dp;
            tdn[i] += dn * dn;
            tl2 += ea*ea + ep*ep + en*en;
        }
    }
    // reduce across the 16 tx lanes (same wave)
    #pragma unroll
    for (int m = 1; m < 16; m <<= 1) {
        tdp[0] += __shfl_xor(tdp[0], m); tdp[1] += __shfl_xor(tdp[1], m);
        tdn[0] += __shfl_xor(tdn[0], m); tdn[1] += __shfl_xor(tdn[1], m);
    }
    if (tx == 0) {
        #pragma unroll
        for (int i = 0; i < 2; ++i) {
            const size_t r = (size_t)rb * 32 + ty*2 + i;
            pdp[(size_t)cb * NROWS + r] = tdp[i];
            pdn[(size_t)cb * NROWS + r] = tdn[i];
        }
    }
    // block reduce tl2
    #pragma unroll
    for (int m = 1; m < 64; m <<= 1) tl2 += __shfl_xor(tl2, m);
    if ((tid & 63) == 0) wred[tid >> 6] = tl2;
    __syncthreads();
    if (tid == 0)
        pl2[(size_t)rb * 16 + cb] = wred[0] + wred[1] + wred[2] + wred[3];
}

// ---------- per-row margins ----------
__global__ __launch_bounds__(256)
void margins_kernel(const float* __restrict__ pdp, const float* __restrict__ pdn,
                    float* __restrict__ margins, float* __restrict__ dd)
{
    const int r = blockIdx.x * 256 + threadIdx.x;
    float dp2 = 0.f, dn2 = 0.f;
    #pragma unroll
    for (int cb = 0; cb < 16; ++cb) {
        dp2 += pdp[(size_t)cb * NROWS + r];
        dn2 += pdn[(size_t)cb * NROWS + r];
    }
    dd[r] = dn2 - dp2;
    margins[r] = (dn2 < dp2) ? (sqrtf(dp2) - sqrtf(dn2)) : 0.f;
}

// ---------- final: l2 sum + radix-select quantile + loss ----------
__global__ __launch_bounds__(1024)
void final_kernel(const float* __restrict__ pl2, int npl2,
                  const float* __restrict__ margins, const float* __restrict__ dd,
                  float* __restrict__ out)
{
    __shared__ unsigned hist[256];
    __shared__ float warp_red[16];
    __shared__ unsigned sh_prefix;
    __shared__ int sh_k;
    __shared__ float sh_l2;
    const int tid = threadIdx.x;

    // --- l2 sum over partials ---
    float l2 = 0.f;
    for (int i = tid; i < npl2; i += 1024) l2 += pl2[i];
    #pragma unroll
    for (int m = 1; m < 64; m <<= 1) l2 += __shfl_xor(l2, m);
    if ((tid & 63) == 0) warp_red[tid >> 6] = l2;
    __syncthreads();
    if (tid == 0) {
        float t = 0.f;
        for (int w = 0; w < 16; ++w) t += warp_red[w];
        sh_l2 = t;
    }
    __syncthreads();

    // --- radix select order stats 8191 and 8192 (margins >= 0 -> uint order ok) ---
    float vsel[2];
    for (int sel = 0; sel < 2; ++sel) {
        if (tid == 0) { sh_k = 8191 + sel; sh_prefix = 0u; }
        __syncthreads();
        for (int shift = 24; shift >= 0; shift -= 8) {
            if (tid < 256) hist[tid] = 0u;
            __syncthreads();
            const unsigned prefix = sh_prefix;
            const unsigned mask = (shift == 24) ? 0u : (0xFFFFFFFFu << (shift + 8));
            for (int i = tid; i < NROWS; i += 1024) {
                const unsigned key = __float_as_uint(margins[i]);
                if (((key ^ prefix) & mask) == 0u)
                    atomicAdd(&hist[(key >> shift) & 255u], 1u);
            }
            __syncthreads();
            if (tid == 0) {
                int kk = sh_k;
                unsigned cum = 0; int d = 0;
                for (; d < 256; ++d) {
                    const unsigned c = hist[d];
                    if (cum + c > (unsigned)kk) break;
                    cum += c;
                }
                sh_prefix = prefix | ((unsigned)d << shift);
                sh_k = kk - (int)cum;
            }
            __syncthreads();
        }
        vsel[sel] = __uint_as_float(sh_prefix);
        __syncthreads();
    }
    const float margin = vsel[0] + 0.75f * (vsel[1] - vsel[0]);

    // --- loss sum ---
    float ssum = 0.f;
    for (int i = tid; i < NROWS; i += 1024) {
        const float t = dd[i] + margin;
        ssum += (t > 0.f) ? t : 0.f;
    }
    #pragma unroll
    for (int m = 1; m < 64; m <<= 1) ssum += __shfl_xor(ssum, m);
    if ((tid & 63) == 0) warp_red[tid >> 6] = ssum;
    __syncthreads();
    if (tid == 0) {
        float S = 0.f;
        for (int w = 0; w < 16; ++w) S += warp_red[w];
        out[0] = S / (float)NROWS + 1e-3f * sh_l2 / (float)NROWS;
    }
}

extern "C" void kernel_launch(void* const* d_in, const int* in_sizes, int n_in,
                              void* d_out, int out_size, void* d_ws, size_t ws_size,
                              hipStream_t stream) {
    (void)in_sizes; (void)n_in; (void)out_size; (void)ws_size;
    const float* item = (const float*)d_in[0];
    const float* pos  = (const float*)d_in[1];
    const float* neg  = (const float*)d_in[2];
    const float* W1   = (const float*)d_in[3];
    const float* b1   = (const float*)d_in[4];
    const float* gam  = (const float*)d_in[5];
    const float* bet  = (const float*)d_in[6];
    const float* rmu  = (const float*)d_in[7];
    const float* rvr  = (const float*)d_in[8];
    const float* W2   = (const float*)d_in[9];
    const float* b2   = (const float*)d_in[10];

    char* ws = (char*)d_ws;
    unsigned short* h = (unsigned short*)ws;                 // 3N*512*2 = 100663296 B
    size_t off = (size_t)M3 * HIDD * sizeof(unsigned short);
    float* pdp = (float*)(ws + off); off += (size_t)16 * NROWS * 4;   // 2 MB
    float* pdn = (float*)(ws + off); off += (size_t)16 * NROWS * 4;   // 2 MB
    float* pl2 = (float*)(ws + off); off += (size_t)16384 * 4;
    float* margins = (float*)(ws + off); off += (size_t)NROWS * 4;
    float* dd = (float*)(ws + off); off += (size_t)NROWS * 4;

    gemm1_kernel<<<dim3(8, M3 / 64), 256, 0, stream>>>(
        item, pos, neg, W1, b1, gam, bet, rmu, rvr, h);
    gemm2_kernel<<<dim3(16, NROWS / 32), 256, 0, stream>>>(
        h, W2, b2, pdp, pdn, pl2);
    margins_kernel<<<dim3(NROWS / 256), 256, 0, stream>>>(pdp, pdn, margins, dd);
    final_kernel<<<1, 1024, 0, stream>>>(pl2, 16384, margins, dd, (float*)d_out);
}

// Round 2
// 595.848 us; speedup vs baseline: 5.0344x; 5.0344x over previous
//
#include <hip/hip_runtime.h>

#define NROWS 32768
#define DIM   1024
#define HIDD  512
#define M3    (3*NROWS)

using bf16x8 = __attribute__((ext_vector_type(8))) short;
using f32x4  = __attribute__((ext_vector_type(4))) float;

// ---------- helpers ----------
static __device__ __forceinline__ unsigned short f2bf(float f) {
    unsigned u = __float_as_uint(f);
    u += 0x7FFFu + ((u >> 16) & 1u);   // round-to-nearest-even
    return (unsigned short)(u >> 16);
}
static __device__ __forceinline__ unsigned cvtpk(float a, float b) {
    unsigned r;
    asm("v_cvt_pk_bf16_f32 %0, %1, %2" : "=v"(r) : "v"(a), "v"(b));
    return r;
}

// ---------- convert fp32 -> bf16 (for W1, W2) ----------
__global__ __launch_bounds__(256)
void cvt_kernel(const float* __restrict__ src, unsigned short* __restrict__ dst, int n4)
{
    const int i = blockIdx.x * 256 + threadIdx.x;
    if (i < n4) {
        float4 v = reinterpret_cast<const float4*>(src)[i];
        uint2 o;
        o.x = cvtpk(v.x, v.y);
        o.y = cvtpk(v.z, v.w);
        reinterpret_cast<uint2*>(dst)[i] = o;
    }
}

// ---------- GEMM1 (MFMA): h = leaky(bn(x @ W1^T + b1)), h bf16 [3N][512] ----------
// grid (4, 768): 128x128 tile, BK=32, 4 waves each own 64x64 (4x4 frags).
__global__ __launch_bounds__(256)
void gemm1_mfma(const float* __restrict__ x0, const float* __restrict__ x1,
                const float* __restrict__ x2,
                const unsigned short* __restrict__ W1bf,
                const float* __restrict__ b1, const float* __restrict__ gamma,
                const float* __restrict__ beta, const float* __restrict__ rmean,
                const float* __restrict__ rvar,
                unsigned short* __restrict__ h)
{
    __shared__ unsigned short Abuf[128*32];
    __shared__ unsigned short Bbuf[128*32];
    const int cb = blockIdx.x;          // 0..3
    const int rb = blockIdx.y;          // 0..767
    const int tid  = threadIdx.x;
    const int lane = tid & 63, w = tid >> 6;
    const int wr = w >> 1, wc = w & 1;
    const int row0 = rb * 128;
    const int s = row0 >> 15;
    const float* x = (s == 0) ? x0 : (s == 1 ? x1 : x2);
    const int rl0 = row0 & (NROWS - 1);
    const int col0 = cb * 128;
    const int l15 = lane & 15, lq = lane >> 4;

    f32x4 acc[4][4] = {};

    for (int k0 = 0; k0 < DIM; k0 += 32) {
        #pragma unroll
        for (int p = 0; p < 4; ++p) {           // stage A: fp32 -> bf16
            const int f = p * 256 + tid;        // 0..1023
            const int r = f >> 3, kq = f & 7;
            float4 v = *reinterpret_cast<const float4*>(
                &x[(size_t)(rl0 + r) * DIM + k0 + kq * 4]);
            uint2 o;
            o.x = cvtpk(v.x, v.y);
            o.y = cvtpk(v.z, v.w);
            *reinterpret_cast<uint2*>(&Abuf[r * 32 + kq * 4]) = o;
        }
        #pragma unroll
        for (int p = 0; p < 2; ++p) {           // stage B (bf16, 16B chunks)
            const int f = p * 256 + tid;        // 0..511
            const int c = f >> 2, kq = f & 3;
            *reinterpret_cast<uint4*>(&Bbuf[c * 32 + kq * 8]) =
                *reinterpret_cast<const uint4*>(&W1bf[(size_t)(col0 + c) * DIM + k0 + kq * 8]);
        }
        __syncthreads();
        bf16x8 af[4], bfv[4];
        #pragma unroll
        for (int m = 0; m < 4; ++m)
            af[m] = *reinterpret_cast<const bf16x8*>(&Abuf[(wr*64 + m*16 + l15) * 32 + lq * 8]);
        #pragma unroll
        for (int n = 0; n < 4; ++n)
            bfv[n] = *reinterpret_cast<const bf16x8*>(&Bbuf[(wc*64 + n*16 + l15) * 32 + lq * 8]);
        #pragma unroll
        for (int m = 0; m < 4; ++m)
            #pragma unroll
            for (int n = 0; n < 4; ++n)
                acc[m][n] = __builtin_amdgcn_mfma_f32_16x16x32_bf16(af[m], bfv[n], acc[m][n], 0, 0, 0);
        __syncthreads();
    }

    // epilogue: BN(eval) + leaky folded to v*A + B per column
    float As[4], Bsc[4];
    #pragma unroll
    for (int n = 0; n < 4; ++n) {
        const int c = col0 + wc*64 + n*16 + l15;
        const float inv = rsqrtf(rvar[c] + 1e-5f);
        As[n]  = inv * gamma[c];
        Bsc[n] = (b1[c] - rmean[c]) * As[n] + beta[c];
    }
    #pragma unroll
    for (int m = 0; m < 4; ++m) {
        const int rbase = row0 + wr*64 + m*16 + lq*4;
        #pragma unroll
        for (int n = 0; n < 4; ++n) {
            const int c = col0 + wc*64 + n*16 + l15;
            #pragma unroll
            for (int i = 0; i < 4; ++i) {
                float v = fmaf(acc[m][n][i], As[n], Bsc[n]);
                v = (v >= 0.f) ? v : 0.1f * v;
                h[(size_t)(rbase + i) * HIDD + c] = f2bf(v);
            }
        }
    }
}

// ---------- GEMM2 (MFMA, fused): e = h @ W2^T + b2 for a/p/n; reduce distances + L2 ----------
// grid (8, 512): 64 batch-rows x 128 cols x 3 streams, BK=32.
// 4 waves: wave w owns cols [w*32, w*32+32) (2 n-frags), all 64 rows (4 m-frags), 3 streams.
__global__ __launch_bounds__(256)
void gemm2_mfma(const unsigned short* __restrict__ h,
                const unsigned short* __restrict__ W2bf,
                const float* __restrict__ b2,
                float* __restrict__ pdp, float* __restrict__ pdn,
                float* __restrict__ pl2)
{
    __shared__ unsigned short Asb[3][64*32];
    __shared__ unsigned short Bsb[128*32];
    __shared__ float dpred[4][64];
    __shared__ float dnred[4][64];
    __shared__ float l2red[4];
    const int cb = blockIdx.x;          // 0..7
    const int rb = blockIdx.y;          // 0..511
    const int tid  = threadIdx.x;
    const int lane = tid & 63, w = tid >> 6;
    const int row0 = rb * 64;
    const int col0 = cb * 128;
    const int l15 = lane & 15, lq = lane >> 4;

    f32x4 acc[3][4][2] = {};

    for (int k0 = 0; k0 < HIDD; k0 += 32) {
        {
            const int r = tid >> 2, kq = tid & 3;
            #pragma unroll
            for (int ss = 0; ss < 3; ++ss)
                *reinterpret_cast<uint4*>(&Asb[ss][r * 32 + kq * 8]) =
                    *reinterpret_cast<const uint4*>(
                        &h[((size_t)ss * NROWS + row0 + r) * HIDD + k0 + kq * 8]);
        }
        #pragma unroll
        for (int p = 0; p < 2; ++p) {
            const int f = p * 256 + tid;
            const int c = f >> 2, kq = f & 3;
            *reinterpret_cast<uint4*>(&Bsb[c * 32 + kq * 8]) =
                *reinterpret_cast<const uint4*>(&W2bf[(size_t)(col0 + c) * HIDD + k0 + kq * 8]);
        }
        __syncthreads();
        bf16x8 bfv[2];
        #pragma unroll
        for (int n = 0; n < 2; ++n)
            bfv[n] = *reinterpret_cast<const bf16x8*>(&Bsb[(w*32 + n*16 + l15) * 32 + lq * 8]);
        #pragma unroll
        for (int ss = 0; ss < 3; ++ss) {
            #pragma unroll
            for (int m = 0; m < 4; ++m) {
                bf16x8 a = *reinterpret_cast<const bf16x8*>(&Asb[ss][(m*16 + l15) * 32 + lq * 8]);
                acc[ss][m][0] = __builtin_amdgcn_mfma_f32_16x16x32_bf16(a, bfv[0], acc[ss][m][0], 0, 0, 0);
                acc[ss][m][1] = __builtin_amdgcn_mfma_f32_16x16x32_bf16(a, bfv[1], acc[ss][m][1], 0, 0, 0);
            }
        }
        __syncthreads();
    }

    // epilogue: distances + L2, never materializing e
    float b2c[2];
    b2c[0] = b2[col0 + w*32 + l15];
    b2c[1] = b2[col0 + w*32 + 16 + l15];
    float l2t = 0.f;
    #pragma unroll
    for (int m = 0; m < 4; ++m) {
        #pragma unroll
        for (int i = 0; i < 4; ++i) {
            float dp = 0.f, dn = 0.f;
            #pragma unroll
            for (int n = 0; n < 2; ++n) {
                const float ea = acc[0][m][n][i] + b2c[n];
                const float ep = acc[1][m][n][i] + b2c[n];
                const float en = acc[2][m][n][i] + b2c[n];
                dp += (ea - ep) * (ea - ep);
                dn += (ea - en) * (ea - en);
                l2t += ea*ea + ep*ep + en*en;
            }
            #pragma unroll
            for (int mm = 1; mm < 16; mm <<= 1) {
                dp += __shfl_xor(dp, mm);
                dn += __shfl_xor(dn, mm);
            }
            if (l15 == 0) {
                dpred[w][m*16 + lq*4 + i] = dp;
                dnred[w][m*16 + lq*4 + i] = dn;
            }
        }
    }
    #pragma unroll
    for (int mm = 1; mm < 64; mm <<= 1) l2t += __shfl_xor(l2t, mm);
    if (lane == 0) l2red[w] = l2t;
    __syncthreads();
    if (tid < 64) {
        const float dp = dpred[0][tid] + dpred[1][tid] + dpred[2][tid] + dpred[3][tid];
        const float dn = dnred[0][tid] + dnred[1][tid] + dnred[2][tid] + dnred[3][tid];
        pdp[(size_t)cb * NROWS + row0 + tid] = dp;
        pdn[(size_t)cb * NROWS + row0 + tid] = dn;
    }
    if (tid == 0)
        pl2[(size_t)rb * 8 + cb] = l2red[0] + l2red[1] + l2red[2] + l2red[3];
}

// ---------- per-row margins ----------
__global__ __launch_bounds__(256)
void margins_kernel(const float* __restrict__ pdp, const float* __restrict__ pdn,
                    float* __restrict__ margins, float* __restrict__ dd)
{
    const int r = blockIdx.x * 256 + threadIdx.x;
    float dp2 = 0.f, dn2 = 0.f;
    #pragma unroll
    for (int cb = 0; cb < 8; ++cb) {
        dp2 += pdp[(size_t)cb * NROWS + r];
        dn2 += pdn[(size_t)cb * NROWS + r];
    }
    dd[r] = dn2 - dp2;
    margins[r] = (dn2 < dp2) ? (sqrtf(dp2) - sqrtf(dn2)) : 0.f;
}

// ---------- final: l2 sum + radix-select quantile + loss ----------
__global__ __launch_bounds__(1024)
void final_kernel(const float* __restrict__ pl2, int npl2,
                  const float* __restrict__ margins, const float* __restrict__ dd,
                  float* __restrict__ out)
{
    __shared__ unsigned hist[256];
    __shared__ float warp_red[16];
    __shared__ unsigned sh_prefix;
    __shared__ int sh_k;
    __shared__ float sh_l2;
    const int tid = threadIdx.x;

    float l2 = 0.f;
    for (int i = tid; i < npl2; i += 1024) l2 += pl2[i];
    #pragma unroll
    for (int m = 1; m < 64; m <<= 1) l2 += __shfl_xor(l2, m);
    if ((tid & 63) == 0) warp_red[tid >> 6] = l2;
    __syncthreads();
    if (tid == 0) {
        float t = 0.f;
        for (int w = 0; w < 16; ++w) t += warp_red[w];
        sh_l2 = t;
    }
    __syncthreads();

    float vsel[2];
    for (int sel = 0; sel < 2; ++sel) {
        if (tid == 0) { sh_k = 8191 + sel; sh_prefix = 0u; }
        __syncthreads();
        for (int shift = 24; shift >= 0; shift -= 8) {
            if (tid < 256) hist[tid] = 0u;
            __syncthreads();
            const unsigned prefix = sh_prefix;
            const unsigned mask = (shift == 24) ? 0u : (0xFFFFFFFFu << (shift + 8));
            for (int i = tid; i < NROWS; i += 1024) {
                const unsigned key = __float_as_uint(margins[i]);
                if (((key ^ prefix) & mask) == 0u)
                    atomicAdd(&hist[(key >> shift) & 255u], 1u);
            }
            __syncthreads();
            if (tid == 0) {
                int kk = sh_k;
                unsigned cum = 0; int d = 0;
                for (; d < 256; ++d) {
                    const unsigned c = hist[d];
                    if (cum + c > (unsigned)kk) break;
                    cum += c;
                }
                sh_prefix = prefix | ((unsigned)d << shift);
                sh_k = kk - (int)cum;
            }
            __syncthreads();
        }
        vsel[sel] = __uint_as_float(sh_prefix);
        __syncthreads();
    }
    const float margin = vsel[0] + 0.75f * (vsel[1] - vsel[0]);

    float ssum = 0.f;
    for (int i = tid; i < NROWS; i += 1024) {
        const float t = dd[i] + margin;
        ssum += (t > 0.f) ? t : 0.f;
    }
    #pragma unroll
    for (int m = 1; m < 64; m <<= 1) ssum += __shfl_xor(ssum, m);
    if ((tid & 63) == 0) warp_red[tid >> 6] = ssum;
    __syncthreads();
    if (tid == 0) {
        float S = 0.f;
        for (int w = 0; w < 16; ++w) S += warp_red[w];
        out[0] = S / (float)NROWS + 1e-3f * sh_l2 / (float)NROWS;
    }
}

extern "C" void kernel_launch(void* const* d_in, const int* in_sizes, int n_in,
                              void* d_out, int out_size, void* d_ws, size_t ws_size,
                              hipStream_t stream) {
    (void)in_sizes; (void)n_in; (void)out_size; (void)ws_size;
    const float* item = (const float*)d_in[0];
    const float* pos  = (const float*)d_in[1];
    const float* neg  = (const float*)d_in[2];
    const float* W1   = (const float*)d_in[3];
    const float* b1   = (const float*)d_in[4];
    const float* gam  = (const float*)d_in[5];
    const float* bet  = (const float*)d_in[6];
    const float* rmu  = (const float*)d_in[7];
    const float* rvr  = (const float*)d_in[8];
    const float* W2   = (const float*)d_in[9];
    const float* b2   = (const float*)d_in[10];

    char* ws = (char*)d_ws;
    unsigned short* h = (unsigned short*)ws;                       // 100,663,296 B
    size_t off = (size_t)M3 * HIDD * sizeof(unsigned short);
    unsigned short* W1bf = (unsigned short*)(ws + off); off += (size_t)HIDD * DIM * 2;   // 1 MB
    unsigned short* W2bf = (unsigned short*)(ws + off); off += (size_t)DIM * HIDD * 2;   // 1 MB
    float* pdp = (float*)(ws + off); off += (size_t)8 * NROWS * 4;   // 1 MB
    float* pdn = (float*)(ws + off); off += (size_t)8 * NROWS * 4;   // 1 MB
    float* pl2 = (float*)(ws + off); off += (size_t)4096 * 4;
    float* margins = (float*)(ws + off); off += (size_t)NROWS * 4;
    float* dd = (float*)(ws + off); off += (size_t)NROWS * 4;

    cvt_kernel<<<dim3((HIDD*DIM/4 + 255)/256), 256, 0, stream>>>(W1, W1bf, HIDD*DIM/4);
    cvt_kernel<<<dim3((DIM*HIDD/4 + 255)/256), 256, 0, stream>>>(W2, W2bf, DIM*HIDD/4);
    gemm1_mfma<<<dim3(4, M3/128), 256, 0, stream>>>(
        item, pos, neg, W1bf, b1, gam, bet, rmu, rvr, h);
    gemm2_mfma<<<dim3(8, NROWS/64), 256, 0, stream>>>(
        h, W2bf, b2, pdp, pdn, pl2);
    margins_kernel<<<dim3(NROWS/256), 256, 0, stream>>>(pdp, pdn, margins, dd);
    final_kernel<<<1, 1024, 0, stream>>>(pl2, 4096, margins, dd, (float*)d_out);
}

// Round 3
// 509.707 us; speedup vs baseline: 5.8852x; 1.1690x over previous
//
#include <hip/hip_runtime.h>

#define NROWS 32768
#define DIM   1024
#define HIDD  512
#define M3    (3*NROWS)

using bf16x8 = __attribute__((ext_vector_type(8))) short;
using f32x4  = __attribute__((ext_vector_type(4))) float;

// ---------- helpers ----------
static __device__ __forceinline__ unsigned short f2bf(float f) {
    unsigned u = __float_as_uint(f);
    u += 0x7FFFu + ((u >> 16) & 1u);   // round-to-nearest-even
    return (unsigned short)(u >> 16);
}
static __device__ __forceinline__ unsigned cvtpk(float a, float b) {
    unsigned r;
    asm("v_cvt_pk_bf16_f32 %0, %1, %2" : "=v"(r) : "v"(a), "v"(b));
    return r;
}
static __device__ __forceinline__ void gload16(const void* gsrc, void* ldst) {
    __builtin_amdgcn_global_load_lds(
        (const __attribute__((address_space(1))) unsigned int*)gsrc,
        (__attribute__((address_space(3))) unsigned int*)ldst,
        16, 0, 0);
}

// ---------- convert fp32 -> bf16 (for W1, W2) ----------
__global__ __launch_bounds__(256)
void cvt_kernel(const float* __restrict__ src, unsigned short* __restrict__ dst, int n4)
{
    const int i = blockIdx.x * 256 + threadIdx.x;
    if (i < n4) {
        float4 v = reinterpret_cast<const float4*>(src)[i];
        uint2 o;
        o.x = cvtpk(v.x, v.y);
        o.y = cvtpk(v.z, v.w);
        reinterpret_cast<uint2*>(dst)[i] = o;
    }
}

// ---------- GEMM1 (MFMA): h = leaky(bn(x @ W1^T + b1)), h bf16 [3N][512] ----------
// 3072 blocks, XCD-swizzled. 128x128 tile, BK=64, 4 waves each own 64x64 (4x4 frags).
__global__ __launch_bounds__(256)
void gemm1_mfma(const float* __restrict__ x0, const float* __restrict__ x1,
                const float* __restrict__ x2,
                const unsigned short* __restrict__ W1bf,
                const float* __restrict__ b1, const float* __restrict__ gamma,
                const float* __restrict__ beta, const float* __restrict__ rmean,
                const float* __restrict__ rvar,
                unsigned short* __restrict__ h)
{
    __shared__ unsigned short Abuf[128*64];      // [r][64], byte ^((r&7)<<4)
    __shared__ unsigned short Bbuf[2*128*32];    // [panel][col][32], chunk-permuted

    const int lin = blockIdx.x;                  // 3072 = 8 XCD * 384
    const int wgid = (lin & 7) * 384 + (lin >> 3);
    const int cb = wgid & 3;                     // 0..3  (adjacent cbs share rb -> same XCD L2)
    const int rb = wgid >> 2;                    // 0..767
    const int tid  = threadIdx.x;
    const int lane = tid & 63, w = tid >> 6;
    const int wr = w >> 1, wc = w & 1;
    const int row0 = rb * 128;
    const int s = row0 >> 15;
    const float* x = (s == 0) ? x0 : (s == 1 ? x1 : x2);
    const int rl0 = row0 & (NROWS - 1);
    const int col0 = cb * 128;
    const int l15 = lane & 15, lq = lane >> 4;

    f32x4 acc[4][4] = {};
    float4 aR[8];

    // prefetch A tile 0 into regs
    #pragma unroll
    for (int p = 0; p < 8; ++p) {
        const int f = p * 256 + tid;            // 0..2047
        const int r = f >> 4, c4 = f & 15;
        aR[p] = *reinterpret_cast<const float4*>(&x[(size_t)(rl0 + r) * DIM + c4 * 4]);
    }

    for (int t = 0; t < 16; ++t) {
        const int k0 = t * 64;
        // ---- stage A (cvt from regs, XOR-swizzled) ----
        #pragma unroll
        for (int p = 0; p < 8; ++p) {
            const int f = p * 256 + tid;
            const int r = f >> 4, c4 = f & 15;
            const unsigned off = (unsigned)((r * 128 + c4 * 8) ^ ((r & 7) << 4));
            uint2 o;
            o.x = cvtpk(aR[p].x, aR[p].y);
            o.y = cvtpk(aR[p].z, aR[p].w);
            *reinterpret_cast<uint2*>(reinterpret_cast<char*>(Abuf) + off) = o;
        }
        // ---- stage B via global_load_lds (source chunk-permuted) ----
        #pragma unroll
        for (int c = 0; c < 4; ++c) {
            const int f = c * 256 + tid;        // 0..1023
            const int panel = f >> 9;
            const int cc = (f >> 2) & 127;
            const int chunk = (f & 3) ^ ((cc >> 1) & 3);
            gload16(&W1bf[(size_t)(col0 + cc) * DIM + k0 + panel * 32 + chunk * 8],
                    reinterpret_cast<char*>(Bbuf) + (size_t)f * 16);
        }
        __syncthreads();
        // ---- issue next A loads (drain hidden under MFMA at next barrier) ----
        if (t < 15) {
            #pragma unroll
            for (int p = 0; p < 8; ++p) {
                const int f = p * 256 + tid;
                const int r = f >> 4, c4 = f & 15;
                aR[p] = *reinterpret_cast<const float4*>(
                    &x[(size_t)(rl0 + r) * DIM + k0 + 64 + c4 * 4]);
            }
        }
        // ---- fragments + MFMA ----
        bf16x8 bfv[2][4];
        #pragma unroll
        for (int kk = 0; kk < 2; ++kk)
            #pragma unroll
            for (int n = 0; n < 4; ++n) {
                const int colr = wc*64 + n*16 + l15;
                const int slq = lq ^ ((colr >> 1) & 3);
                bfv[kk][n] = *reinterpret_cast<const bf16x8*>(
                    reinterpret_cast<char*>(Bbuf) + kk*8192 + colr*64 + slq*16);
            }
        #pragma unroll
        for (int kk = 0; kk < 2; ++kk)
            #pragma unroll
            for (int m = 0; m < 4; ++m) {
                const int row = wr*64 + m*16 + l15;
                const unsigned ab = (unsigned)((row*128 + kk*64 + lq*16) ^ ((row & 7) << 4));
                bf16x8 af = *reinterpret_cast<const bf16x8*>(
                    reinterpret_cast<char*>(Abuf) + ab);
                #pragma unroll
                for (int n = 0; n < 4; ++n)
                    acc[m][n] = __builtin_amdgcn_mfma_f32_16x16x32_bf16(af, bfv[kk][n], acc[m][n], 0, 0, 0);
            }
        __syncthreads();
    }

    // epilogue: BN(eval) + leaky folded to v*A + B per column
    float As[4], Bsc[4];
    #pragma unroll
    for (int n = 0; n < 4; ++n) {
        const int c = col0 + wc*64 + n*16 + l15;
        const float inv = rsqrtf(rvar[c] + 1e-5f);
        As[n]  = inv * gamma[c];
        Bsc[n] = (b1[c] - rmean[c]) * As[n] + beta[c];
    }
    #pragma unroll
    for (int m = 0; m < 4; ++m) {
        const int rbase = row0 + wr*64 + m*16 + lq*4;
        #pragma unroll
        for (int n = 0; n < 4; ++n) {
            const int c = col0 + wc*64 + n*16 + l15;
            #pragma unroll
            for (int i = 0; i < 4; ++i) {
                float v = fmaf(acc[m][n][i], As[n], Bsc[n]);
                v = (v >= 0.f) ? v : 0.1f * v;
                h[(size_t)(rbase + i) * HIDD + c] = f2bf(v);
            }
        }
    }
}

// ---------- GEMM2 (MFMA, fused): e = h @ W2^T + b2 for a/p/n; reduce distances + L2 ----------
// 4096 blocks XCD-swizzled; 64 batch-rows x 128 cols x 3 streams, BK=64, 512 thr / 8 waves.
__global__ __launch_bounds__(512)
void gemm2_mfma(const unsigned short* __restrict__ h,
                const unsigned short* __restrict__ W2bf,
                const float* __restrict__ b2,
                float* __restrict__ pdp, float* __restrict__ pdn,
                float* __restrict__ pl2)
{
    __shared__ unsigned short Asb[3*2*64*32];    // [s][panel][r][32], chunk-permuted
    __shared__ unsigned short Bsb[2*128*32];     // [panel][col][32], chunk-permuted
    __shared__ float dpred[8][64];
    __shared__ float dnred[8][64];
    __shared__ float l2red[8];

    const int lin = blockIdx.x;                  // 4096 = 8 * 512
    const int wgid = (lin & 7) * 512 + (lin >> 3);
    const int cb = wgid & 7;                     // 0..7
    const int rb = wgid >> 3;                    // 0..511
    const int tid  = threadIdx.x;
    const int lane = tid & 63, w = tid >> 6;     // 8 waves, wave owns cols w*16..+16
    const int row0 = rb * 64;
    const int col0 = cb * 128;
    const int l15 = lane & 15, lq = lane >> 4;

    f32x4 acc[3][4] = {};

    for (int t = 0; t < 8; ++t) {
        const int k0 = t * 64;
        // ---- A (h, 3 streams) via global_load_lds ----
        #pragma unroll
        for (int c = 0; c < 3; ++c) {
            const int f = c * 512 + tid;         // 0..1535
            const int s = f >> 9;
            const int rem = f & 511;
            const int panel = rem >> 8;
            const int r = (rem >> 2) & 63;
            const int chunk = (rem & 3) ^ ((r >> 1) & 3);
            gload16(&h[((size_t)s * NROWS + row0 + r) * HIDD + k0 + panel * 32 + chunk * 8],
                    reinterpret_cast<char*>(Asb) + (size_t)f * 16);
        }
        // ---- B (W2) ----
        #pragma unroll
        for (int c = 0; c < 2; ++c) {
            const int f = c * 512 + tid;         // 0..1023
            const int panel = f >> 9;
            const int cc = (f >> 2) & 127;
            const int chunk = (f & 3) ^ ((cc >> 1) & 3);
            gload16(&W2bf[(size_t)(col0 + cc) * HIDD + k0 + panel * 32 + chunk * 8],
                    reinterpret_cast<char*>(Bsb) + (size_t)f * 16);
        }
        __syncthreads();
        bf16x8 bfv[2];
        #pragma unroll
        for (int kk = 0; kk < 2; ++kk) {
            const int colr = w*16 + l15;
            const int slq = lq ^ ((colr >> 1) & 3);
            bfv[kk] = *reinterpret_cast<const bf16x8*>(
                reinterpret_cast<char*>(Bsb) + kk*8192 + colr*64 + slq*16);
        }
        #pragma unroll
        for (int s = 0; s < 3; ++s)
            #pragma unroll
            for (int m = 0; m < 4; ++m) {
                const int r = m*16 + l15;
                const int slq = lq ^ ((r >> 1) & 3);
                #pragma unroll
                for (int kk = 0; kk < 2; ++kk) {
                    bf16x8 a = *reinterpret_cast<const bf16x8*>(
                        reinterpret_cast<char*>(Asb) + s*8192 + kk*4096 + r*64 + slq*16);
                    acc[s][m] = __builtin_amdgcn_mfma_f32_16x16x32_bf16(a, bfv[kk], acc[s][m], 0, 0, 0);
                }
            }
        __syncthreads();
    }

    // epilogue: distances + L2, never materializing e
    const float b2c = b2[col0 + w*16 + l15];
    float l2t = 0.f;
    #pragma unroll
    for (int m = 0; m < 4; ++m) {
        #pragma unroll
        for (int i = 0; i < 4; ++i) {
            const float ea = acc[0][m][i] + b2c;
            const float ep = acc[1][m][i] + b2c;
            const float en = acc[2][m][i] + b2c;
            float dp = (ea - ep) * (ea - ep);
            float dn = (ea - en) * (ea - en);
            l2t += ea*ea + ep*ep + en*en;
            #pragma unroll
            for (int mm = 1; mm < 16; mm <<= 1) {
                dp += __shfl_xor(dp, mm);
                dn += __shfl_xor(dn, mm);
            }
            if (l15 == 0) {
                dpred[w][m*16 + lq*4 + i] = dp;
                dnred[w][m*16 + lq*4 + i] = dn;
            }
        }
    }
    #pragma unroll
    for (int mm = 1; mm < 64; mm <<= 1) l2t += __shfl_xor(l2t, mm);
    if (lane == 0) l2red[w] = l2t;
    __syncthreads();
    if (tid < 64) {
        float dp = 0.f, dn = 0.f;
        #pragma unroll
        for (int ww = 0; ww < 8; ++ww) { dp += dpred[ww][tid]; dn += dnred[ww][tid]; }
        pdp[(size_t)cb * NROWS + row0 + tid] = dp;
        pdn[(size_t)cb * NROWS + row0 + tid] = dn;
    }
    if (tid == 0) {
        float t = 0.f;
        #pragma unroll
        for (int ww = 0; ww < 8; ++ww) t += l2red[ww];
        pl2[(size_t)rb * 8 + cb] = t;
    }
}

// ---------- per-row margins ----------
__global__ __launch_bounds__(256)
void margins_kernel(const float* __restrict__ pdp, const float* __restrict__ pdn,
                    float* __restrict__ margins, float* __restrict__ dd)
{
    const int r = blockIdx.x * 256 + threadIdx.x;
    float dp2 = 0.f, dn2 = 0.f;
    #pragma unroll
    for (int cb = 0; cb < 8; ++cb) {
        dp2 += pdp[(size_t)cb * NROWS + r];
        dn2 += pdn[(size_t)cb * NROWS + r];
    }
    dd[r] = dn2 - dp2;
    margins[r] = (dn2 < dp2) ? (sqrtf(dp2) - sqrtf(dn2)) : 0.f;
}

// ---------- final: l2 sum + radix-select quantile + loss ----------
__global__ __launch_bounds__(1024)
void final_kernel(const float* __restrict__ pl2, int npl2,
                  const float* __restrict__ margins, const float* __restrict__ dd,
                  float* __restrict__ out)
{
    __shared__ unsigned hist[256];
    __shared__ float warp_red[16];
    __shared__ unsigned sh_prefix;
    __shared__ int sh_k;
    __shared__ float sh_l2;
    const int tid = threadIdx.x;

    float l2 = 0.f;
    for (int i = tid; i < npl2; i += 1024) l2 += pl2[i];
    #pragma unroll
    for (int m = 1; m < 64; m <<= 1) l2 += __shfl_xor(l2, m);
    if ((tid & 63) == 0) warp_red[tid >> 6] = l2;
    __syncthreads();
    if (tid == 0) {
        float t = 0.f;
        for (int w = 0; w < 16; ++w) t += warp_red[w];
        sh_l2 = t;
    }
    __syncthreads();

    float vsel[2];
    for (int sel = 0; sel < 2; ++sel) {
        if (tid == 0) { sh_k = 8191 + sel; sh_prefix = 0u; }
        __syncthreads();
        for (int shift = 24; shift >= 0; shift -= 8) {
            if (tid < 256) hist[tid] = 0u;
            __syncthreads();
            const unsigned prefix = sh_prefix;
            const unsigned mask = (shift == 24) ? 0u : (0xFFFFFFFFu << (shift + 8));
            for (int i = tid; i < NROWS; i += 1024) {
                const unsigned key = __float_as_uint(margins[i]);
                if (((key ^ prefix) & mask) == 0u)
                    atomicAdd(&hist[(key >> shift) & 255u], 1u);
            }
            __syncthreads();
            if (tid == 0) {
                int kk = sh_k;
                unsigned cum = 0; int d = 0;
                for (; d < 256; ++d) {
                    const unsigned c = hist[d];
                    if (cum + c > (unsigned)kk) break;
                    cum += c;
                }
                sh_prefix = prefix | ((unsigned)d << shift);
                sh_k = kk - (int)cum;
            }
            __syncthreads();
        }
        vsel[sel] = __uint_as_float(sh_prefix);
        __syncthreads();
    }
    const float margin = vsel[0] + 0.75f * (vsel[1] - vsel[0]);

    float ssum = 0.f;
    for (int i = tid; i < NROWS; i += 1024) {
        const float t = dd[i] + margin;
        ssum += (t > 0.f) ? t : 0.f;
    }
    #pragma unroll
    for (int m = 1; m < 64; m <<= 1) ssum += __shfl_xor(ssum, m);
    if ((tid & 63) == 0) warp_red[tid >> 6] = ssum;
    __syncthreads();
    if (tid == 0) {
        float S = 0.f;
        for (int w = 0; w < 16; ++w) S += warp_red[w];
        out[0] = S / (float)NROWS + 1e-3f * sh_l2 / (float)NROWS;
    }
}

extern "C" void kernel_launch(void* const* d_in, const int* in_sizes, int n_in,
                              void* d_out, int out_size, void* d_ws, size_t ws_size,
                              hipStream_t stream) {
    (void)in_sizes; (void)n_in; (void)out_size; (void)ws_size;
    const float* item = (const float*)d_in[0];
    const float* pos  = (const float*)d_in[1];
    const float* neg  = (const float*)d_in[2];
    const float* W1   = (const float*)d_in[3];
    const float* b1   = (const float*)d_in[4];
    const float* gam  = (const float*)d_in[5];
    const float* bet  = (const float*)d_in[6];
    const float* rmu  = (const float*)d_in[7];
    const float* rvr  = (const float*)d_in[8];
    const float* W2   = (const float*)d_in[9];
    const float* b2   = (const float*)d_in[10];

    char* ws = (char*)d_ws;
    unsigned short* h = (unsigned short*)ws;                       // 100,663,296 B
    size_t off = (size_t)M3 * HIDD * sizeof(unsigned short);
    unsigned short* W1bf = (unsigned short*)(ws + off); off += (size_t)HIDD * DIM * 2;
    unsigned short* W2bf = (unsigned short*)(ws + off); off += (size_t)DIM * HIDD * 2;
    float* pdp = (float*)(ws + off); off += (size_t)8 * NROWS * 4;
    float* pdn = (float*)(ws + off); off += (size_t)8 * NROWS * 4;
    float* pl2 = (float*)(ws + off); off += (size_t)4096 * 4;
    float* margins = (float*)(ws + off); off += (size_t)NROWS * 4;
    float* dd = (float*)(ws + off); off += (size_t)NROWS * 4;

    cvt_kernel<<<dim3((HIDD*DIM/4 + 255)/256), 256, 0, stream>>>(W1, W1bf, HIDD*DIM/4);
    cvt_kernel<<<dim3((DIM*HIDD/4 + 255)/256), 256, 0, stream>>>(W2, W2bf, DIM*HIDD/4);
    gemm1_mfma<<<dim3(3072), 256, 0, stream>>>(
        item, pos, neg, W1bf, b1, gam, bet, rmu, rvr, h);
    gemm2_mfma<<<dim3(4096), 512, 0, stream>>>(
        h, W2bf, b2, pdp, pdn, pl2);
    margins_kernel<<<dim3(NROWS/256), 256, 0, stream>>>(pdp, pdn, margins, dd);
    final_kernel<<<1, 1024, 0, stream>>>(pl2, 4096, margins, dd, (float*)d_out);
}